// Round 17
// baseline (59.889 us; speedup 1.0000x reference)
//
#include <hip/hip_runtime.h>

#define KN 32
#define DF 128
#define WPB 4    // waves per block (independent waves, no cross-wave sync)

typedef float  f32x16 __attribute__((ext_vector_type(16)));
typedef float  f32x2  __attribute__((ext_vector_type(2)));
typedef short  s16x8  __attribute__((ext_vector_type(8)));

union ldsu { int4 i; s16x8 v; };

__device__ __forceinline__ unsigned int pk_bf16(float lo, float hi) {
    unsigned int r;
    asm("v_cvt_pk_bf16_f32 %0, %1, %2" : "=v"(r) : "v"(lo), "v"(hi));
    return r;
}
// exp2 — featbf is pre-scaled by sqrt(log2 e), so exp(L-m) == exp2(L'-m').
__device__ __forceinline__ float ex2(float x) {
    float r; asm("v_exp_f32 %0, %1" : "=v"(r) : "v"(x)); return r;
}
__device__ __forceinline__ float bflo(unsigned int u) { return __uint_as_float(u << 16); }
__device__ __forceinline__ float bfhi(unsigned int u) { return __uint_as_float(u & 0xffff0000u); }

// global -> LDS direct copy, 16B per lane; LDS dest = base + lane*16 (HW rule).
__device__ __forceinline__ void gll16(const void* g, void* l) {
    __builtin_amdgcn_global_load_lds(
        (const __attribute__((address_space(1))) unsigned int*)g,
        (__attribute__((address_space(3))) unsigned int*)l,
        16, 0, 0);
}

// ---- Prepass: feat fp32 -> bf16 copy scaled by sqrt(log2 e) (MFMA operands;
// scale cancels in softmax via exp2) + fp8 copy UNSCALED (phase E values).
__global__ __launch_bounds__(256)
void cvt_kernel(const float* __restrict__ f, unsigned short* __restrict__ bf,
                unsigned char* __restrict__ f8, int n8) {
    const int i = blockIdx.x * blockDim.x + threadIdx.x;   // 8 floats per thread
    if (i >= n8) return;
    const float s = 1.20112240872f;   // sqrt(log2(e)); L' = log2e * L exactly
    float4 x0 = ((const float4*)f)[2 * i];
    float4 x1 = ((const float4*)f)[2 * i + 1];
    int4 b;
    b.x = (int)pk_bf16(s * x0.x, s * x0.y); b.y = (int)pk_bf16(s * x0.z, s * x0.w);
    b.z = (int)pk_bf16(s * x1.x, s * x1.y); b.w = (int)pk_bf16(s * x1.z, s * x1.w);
    ((int4*)bf)[i] = b;
    int p0 = __builtin_amdgcn_cvt_pk_fp8_f32(x0.x, x0.y, 0, false);
    p0     = __builtin_amdgcn_cvt_pk_fp8_f32(x0.z, x0.w, p0, true);
    int p1 = __builtin_amdgcn_cvt_pk_fp8_f32(x1.x, x1.y, 0, false);
    p1     = __builtin_amdgcn_cvt_pk_fp8_f32(x1.z, x1.w, p1, true);
    ((int2*)f8)[i] = make_int2(p0, p1);
}

// ---- Main: round-16 per-wave code exactly; WPB raised 2->4 (256-thread
// blocks of 4 INDEPENDENT waves). Theory: resident-block equilibrium (~8
// blocks/CU across all prior rounds) is workgroup-granular, so fatter blocks
// double resident waves. Zero cross-wave synchronization.
__global__ __launch_bounds__(WPB * 64, 1)
void coattn_kernel(const float* __restrict__ feat,
                   const unsigned char* __restrict__ featbf,   // bf16 rows, 256B each (scaled)
                   const unsigned char* __restrict__ feat8,    // fp8 rows, 128B each
                   const int* __restrict__ sim_idx,
                   const int* __restrict__ cor_idx,
                   float* __restrict__ out, int nnodes) {
    // [wave][row 32][chunk 8] x 16B = 4KB per wave (one matrix K-half at a time)
    __shared__ int4 Ls[WPB][KN][8];
    const int wv = threadIdx.x >> 6;
    const int l  = threadIdx.x & 63;
    const int c  = l & 31;   // neighbor row owned by this lane (MFMA row/col)
    const int h  = l >> 5;   // wave half
    const int g  = l >> 3;   // cooperative row group 0..7
    const int m  = l & 7;    // 16B chunk within half-row
    const int n  = blockIdx.x * WPB + wv;
    if (n >= nnodes) return;

    const int si = sim_idx[n * KN + c];
    const int ci = cor_idx[n * KN + c];
    const unsigned pidx = ((unsigned)ci << 16) | (unsigned)si;   // both < 2^16
    // Pre-swizzled source chunk (involution m^g): reader XORs with c&7.
    const unsigned swz = (unsigned)(((m ^ g) & 7) * 16);

    // ---- Phase A+C: per K-half: stage D -> read fD, stage Q -> MFMA.
    // Fragment layout for mfma_f32_32x32x16_bf16: lane (c,h) holds row c,
    // k = h*8+e per K=16 step s -> 16B chunk (sp*2+h) of the half.
    f32x16 acc  = {0,0,0,0,0,0,0,0,0,0,0,0,0,0,0,0};
    f32x16 accT = {0,0,0,0,0,0,0,0,0,0,0,0,0,0,0,0};
    unsigned spk[4];
    #pragma unroll
    for (int t = 0; t < 4; ++t) spk[t] = (unsigned)__shfl((int)pidx, 8 * t + g, 64);
    #pragma unroll
    for (int H = 0; H < 2; ++H) {
        const unsigned hoff = (unsigned)(H * 128) + swz;
        // -- D stage
        #pragma unroll
        for (int t = 0; t < 4; ++t)
            gll16(featbf + (spk[t] & 0xffffu) * 256u + hoff, (void*)&Ls[wv][8 * t][0]);
        asm volatile("s_waitcnt vmcnt(0)" ::: "memory");   // LDS writes landed
        __builtin_amdgcn_sched_barrier(0);
        s16x8 fD[4];
        #pragma unroll
        for (int sp = 0; sp < 4; ++sp) {
            union ldsu u; u.i = Ls[wv][c][(sp * 2 + h) ^ (c & 7)];
            fD[sp] = u.v;
        }
        asm volatile("s_waitcnt lgkmcnt(0)" ::: "memory"); // WAR: D reads done
        __builtin_amdgcn_sched_barrier(0);
        // -- Q stage (overwrites buffer)
        #pragma unroll
        for (int t = 0; t < 4; ++t)
            gll16(featbf + (spk[t] >> 16) * 256u + hoff, (void*)&Ls[wv][8 * t][0]);
        asm volatile("s_waitcnt vmcnt(0)" ::: "memory");
        __builtin_amdgcn_sched_barrier(0);
        #pragma unroll
        for (int sp = 0; sp < 4; ++sp) {
            union ldsu uQ; uQ.i = Ls[wv][c][(sp * 2 + h) ^ (c & 7)];
            acc  = __builtin_amdgcn_mfma_f32_32x32x16_bf16(fD[sp], uQ.v, acc,  0, 0, 0);
            accT = __builtin_amdgcn_mfma_f32_32x32x16_bf16(uQ.v, fD[sp], accT, 0, 0, 0);
        }
        asm volatile("s_waitcnt lgkmcnt(0)" ::: "memory"); // WAR before next stage
        __builtin_amdgcn_sched_barrier(0);
    }
    // C layout: elem p at M[row=(p&3)+8*(p>>2)+4*h][col=c]
    // acc[p] = L'[kp][c], accT[p] = L'[c][jp]  (L' = log2e * L)

    // ---- Phase D (exp2 domain, numerically safe). Column stats for col c:
    // round mx to bf16 FIRST, compute z against the rounded max -> the packed
    // bf16 (invZ,mx) shuffle stays exactly self-consistent. Args <= ~0.5,
    // denominators >= 1: safe even for collision diagonals (L' ~ 185).
    float mx = acc[0];
    #pragma unroll
    for (int p = 1; p < 16; ++p) mx = fmaxf(mx, acc[p]);
    mx = fmaxf(mx, __shfl_xor(mx, 32, 64));
    const float mxf = bfhi(pk_bf16(0.f, mx));          // bf16-rounded max (RNE)
    float z = 0.f;
    #pragma unroll
    for (int p = 0; p < 16; ++p) z += ex2(acc[p] - mxf);
    z += __shfl_xor(z, 32, 64);
    const unsigned pcol = pk_bf16(1.0f / z, mxf);      // lo=bf16(invZ), hi=bf16(mx)

    float rm = accT[0];
    #pragma unroll
    for (int p = 1; p < 16; ++p) rm = fmaxf(rm, accT[p]);
    rm = fmaxf(rm, __shfl_xor(rm, 32, 64));
    const float rmf = bfhi(pk_bf16(0.f, rm));
    float rs = 0.f;
    #pragma unroll
    for (int p = 0; p < 16; ++p) rs += ex2(accT[p] - rmf);
    rs += __shfl_xor(rs, 32, 64);

    // w[b=c] = sum_a exp2(L'[b][a]-mx_a) * invZ_a   (one packed shuffle per p)
    float w = 0.f;
    #pragma unroll
    for (int p = 0; p < 16; ++p) {
        const int jp = (p & 3) + 8 * (p >> 2) + 4 * h;
        const unsigned pc = (unsigned)__shfl((int)pcol, jp, 64);
        w += ex2(accT[p] - bfhi(pc)) * bflo(pc);
    }
    w += __shfl_xor(w, 32, 64);

    // v[j=c] = sum_b u_b * exp2(L'[b][j]-rm_b),  u = w/rs  (packed shuffle)
    const unsigned prow = pk_bf16(w / rs, rmf);        // lo=bf16(u), hi=bf16(rm)
    float v = 0.f;
    #pragma unroll
    for (int p = 0; p < 16; ++p) {
        const int kp = (p & 3) + 8 * (p >> 2) + 4 * h;
        const unsigned pr = (unsigned)__shfl((int)prow, kp, 64);
        v += ex2(acc[p] - bfhi(pr)) * bflo(pr);
    }
    v += __shfl_xor(v, 32, 64);

    // ---- Phase E: weighted row-sums from the fp8 copy (2.56MB, L2-resident;
    // one 128B line per half-wave load). Packed (v,w) + packed index shuffles;
    // f32x2 accumulation (v_pk_fma_f32). Lane covers dims 4c..4c+3.
    const unsigned pwv = pk_bf16(v, w);                // lo=bf16(v), hi=bf16(w)
    f32x2 sQ2[2] = {{0.f,0.f},{0.f,0.f}};
    f32x2 sD2[2] = {{0.f,0.f},{0.f,0.f}};
    f32x2 sC2[2] = {{0.f,0.f},{0.f,0.f}};
    #pragma unroll
    for (int t = 0; t < 16; ++t) {
        const int b = h * 16 + t;
        const unsigned pi = (unsigned)__shfl((int)pidx, b, 64);
        const unsigned pv = (unsigned)__shfl((int)pwv,  b, 64);
        const float wb = bfhi(pv);
        const float vb = bflo(pv);
        const unsigned int da = *(const unsigned int*)(feat8 + ((pi & 0xffffu) << 7) + 4u * c);
        const unsigned int dq = *(const unsigned int*)(feat8 + ((pi >> 16) << 7) + 4u * c);
        f32x2 a01 = __builtin_amdgcn_cvt_pk_f32_fp8((int)da, false);
        f32x2 a23 = __builtin_amdgcn_cvt_pk_f32_fp8((int)da, true);
        f32x2 q01 = __builtin_amdgcn_cvt_pk_f32_fp8((int)dq, false);
        f32x2 q23 = __builtin_amdgcn_cvt_pk_f32_fp8((int)dq, true);
        const f32x2 wb2 = {wb, wb};
        const f32x2 vb2 = {vb, vb};
        sQ2[0] += q01;                sQ2[1] += q23;
        sD2[0] = wb2 * a01 + sD2[0];  sD2[1] = wb2 * a23 + sD2[1];
        sC2[0] = vb2 * q01 + sC2[0];  sC2[1] = vb2 * q23 + sC2[1];
    }
    #pragma unroll
    for (int i = 0; i < 2; ++i) {
        sQ2[i][0] += __shfl_xor(sQ2[i][0], 32, 64); sQ2[i][1] += __shfl_xor(sQ2[i][1], 32, 64);
        sD2[i][0] += __shfl_xor(sD2[i][0], 32, 64); sD2[i][1] += __shfl_xor(sD2[i][1], 32, 64);
        sC2[i][0] += __shfl_xor(sC2[i][0], 32, 64); sC2[i][1] += __shfl_xor(sC2[i][1], 32, 64);
    }

    // ---- Phase F: pooling via S_sh overlaid on this wave's (retired) staging
    // buffer; intra-wave lgkm fence, no barrier.
    float* const S_sh = (float*)Ls[wv];
    if (h == 0) {
        *(float4*)&S_sh[0 * DF + 4 * c] = make_float4(sQ2[0][0], sQ2[0][1], sQ2[1][0], sQ2[1][1]);
        *(float4*)&S_sh[1 * DF + 4 * c] = make_float4(sD2[0][0], sD2[0][1], sD2[1][0], sD2[1][1]);
        *(float4*)&S_sh[2 * DF + 4 * c] = make_float4(sC2[0][0], sC2[0][1], sC2[1][0], sC2[1][1]);
    }
    asm volatile("s_waitcnt lgkmcnt(0)" ::: "memory");
    const float h0 = S_sh[6 * l + 0] + S_sh[6 * l + 1] + S_sh[6 * l + 2];
    const float h1 = S_sh[6 * l + 3] + S_sh[6 * l + 4] + S_sh[6 * l + 5];
    const float* fr = feat + (long)n * DF;
    const float o0 = fr[2 * l + 0] + h0 * (1.0f / 96.0f);
    const float o1 = fr[2 * l + 1] + h1 * (1.0f / 96.0f);
    *(float2*)&out[(long)n * DF + 2 * l] = make_float2(o0, o1);
}

// ---- Fallback (round-4 kernel, fp32-direct): used only if ws_size is too small.
#define RP 136
__global__ __launch_bounds__(64, 2)
void coattn_v4(const float* __restrict__ feat,
               const int* __restrict__ sim_idx,
               const int* __restrict__ cor_idx,
               float* __restrict__ out, int nnodes) {
    __shared__ unsigned char lds[2 * KN * RP];
    unsigned char* Ab8 = lds;
    unsigned char* Bb8 = lds + KN * RP;
    float* S_sh = (float*)lds;
    const int n = blockIdx.x;
    const int l = threadIdx.x;
    const int c = l & 31;
    const int h = l >> 5;
    const int si = sim_idx[n * KN + c];
    const int ci = cor_idx[n * KN + c];
    const float* Dr = feat + (long)si * DF;
    const float* Qr = feat + (long)ci * DF;
    f32x16 acc  = {0,0,0,0,0,0,0,0,0,0,0,0,0,0,0,0};
    f32x16 accT = {0,0,0,0,0,0,0,0,0,0,0,0,0,0,0,0};
    #pragma unroll
    for (int s = 0; s < 8; ++s) {
        const int d0 = s * 16 + h * 8;
        float4 a0 = *(const float4*)(Dr + d0);
        float4 a1 = *(const float4*)(Dr + d0 + 4);
        float4 b0 = *(const float4*)(Qr + d0);
        float4 b1 = *(const float4*)(Qr + d0 + 4);
        union { s16x8 v8; unsigned int u[4]; } ua, ub;
        ua.u[0] = pk_bf16(a0.x, a0.y); ua.u[1] = pk_bf16(a0.z, a0.w);
        ua.u[2] = pk_bf16(a1.x, a1.y); ua.u[3] = pk_bf16(a1.z, a1.w);
        ub.u[0] = pk_bf16(b0.x, b0.y); ub.u[1] = pk_bf16(b0.z, b0.w);
        ub.u[2] = pk_bf16(b1.x, b1.y); ub.u[3] = pk_bf16(b1.z, b1.w);
        acc  = __builtin_amdgcn_mfma_f32_32x32x16_bf16(ua.v8, ub.v8, acc,  0, 0, 0);
        accT = __builtin_amdgcn_mfma_f32_32x32x16_bf16(ub.v8, ua.v8, accT, 0, 0, 0);
        int pa0 = __builtin_amdgcn_cvt_pk_fp8_f32(a0.x, a0.y, 0, false);
        pa0     = __builtin_amdgcn_cvt_pk_fp8_f32(a0.z, a0.w, pa0, true);
        int pa1 = __builtin_amdgcn_cvt_pk_fp8_f32(a1.x, a1.y, 0, false);
        pa1     = __builtin_amdgcn_cvt_pk_fp8_f32(a1.z, a1.w, pa1, true);
        int pb0 = __builtin_amdgcn_cvt_pk_fp8_f32(b0.x, b0.y, 0, false);
        pb0     = __builtin_amdgcn_cvt_pk_fp8_f32(b0.z, b0.w, pb0, true);
        int pb1 = __builtin_amdgcn_cvt_pk_fp8_f32(b1.x, b1.y, 0, false);
        pb1     = __builtin_amdgcn_cvt_pk_fp8_f32(b1.z, b1.w, pb1, true);
        *(int2*)(Ab8 + c * RP + d0) = make_int2(pa0, pa1);
        *(int2*)(Bb8 + c * RP + d0) = make_int2(pb0, pb1);
    }
    float mx = acc[0];
    #pragma unroll
    for (int p = 1; p < 16; ++p) mx = fmaxf(mx, acc[p]);
    mx = fmaxf(mx, __shfl_xor(mx, 32, 64));
    float z = 0.f;
    #pragma unroll
    for (int p = 0; p < 16; ++p) z += __expf(acc[p] - mx);
    z += __shfl_xor(z, 32, 64);
    const float invZ = 1.0f / z;
    float rm = accT[0];
    #pragma unroll
    for (int p = 1; p < 16; ++p) rm = fmaxf(rm, accT[p]);
    rm = fmaxf(rm, __shfl_xor(rm, 32, 64));
    float rs = 0.f;
    #pragma unroll
    for (int p = 0; p < 16; ++p) rs += __expf(accT[p] - rm);
    rs += __shfl_xor(rs, 32, 64);
    const float invR = 1.0f / rs;
    float w = 0.f;
    #pragma unroll
    for (int p = 0; p < 16; ++p) {
        const int jp = (p & 3) + 8 * (p >> 2) + 4 * h;
        w += __expf(accT[p] - __shfl(mx, jp, 64)) * __shfl(invZ, jp, 64);
    }
    w += __shfl_xor(w, 32, 64);
    const float u = w * invR;
    float v = 0.f;
    #pragma unroll
    for (int p = 0; p < 16; ++p) {
        const int kp = (p & 3) + 8 * (p >> 2) + 4 * h;
        v += __expf(acc[p] - __shfl(rm, kp, 64)) * __shfl(u, kp, 64);
    }
    v += __shfl_xor(v, 32, 64);
    __syncthreads();
    float sQ[4] = {0,0,0,0}, sD[4] = {0,0,0,0}, sC[4] = {0,0,0,0};
    const unsigned char* Abase = Ab8 + h * 16 * RP + 4 * c;
    const unsigned char* Bbase = Bb8 + h * 16 * RP + 4 * c;
    #pragma unroll
    for (int t = 0; t < 16; ++t) {
        const int b = h * 16 + t;
        const float wb = __shfl(w, b, 64);
        const float vb = __shfl(v, b, 64);
        const unsigned int da = *(const unsigned int*)(Abase + t * RP);
        const unsigned int dq = *(const unsigned int*)(Bbase + t * RP);
        f32x2 a01 = __builtin_amdgcn_cvt_pk_f32_fp8((int)da, false);
        f32x2 a23 = __builtin_amdgcn_cvt_pk_f32_fp8((int)da, true);
        f32x2 q01 = __builtin_amdgcn_cvt_pk_f32_fp8((int)dq, false);
        f32x2 q23 = __builtin_amdgcn_cvt_pk_f32_fp8((int)dq, true);
        sQ[0] += q01[0]; sQ[1] += q01[1]; sQ[2] += q23[0]; sQ[3] += q23[1];
        sD[0] = fmaf(wb, a01[0], sD[0]); sD[1] = fmaf(wb, a01[1], sD[1]);
        sD[2] = fmaf(wb, a23[0], sD[2]); sD[3] = fmaf(wb, a23[1], sD[3]);
        sC[0] = fmaf(vb, q01[0], sC[0]); sC[1] = fmaf(vb, q01[1], sC[1]);
        sC[2] = fmaf(vb, q23[0], sC[2]);
        sC[3] = fmaf(vb, q23[1], sC[3]);
    }
    #pragma unroll
    for (int i = 0; i < 4; ++i) {
        sQ[i] += __shfl_xor(sQ[i], 32, 64);
        sD[i] += __shfl_xor(sD[i], 32, 64);
        sC[i] += __shfl_xor(sC[i], 32, 64);
    }
    __syncthreads();
    if (h == 0) {
        *(float4*)&S_sh[0 * DF + 4 * c] = make_float4(sQ[0], sQ[1], sQ[2], sQ[3]);
        *(float4*)&S_sh[1 * DF + 4 * c] = make_float4(sD[0], sD[1], sD[2], sD[3]);
        *(float4*)&S_sh[2 * DF + 4 * c] = make_float4(sC[0], sC[1], sC[2], sC[3]);
    }
    __syncthreads();
    const float h0 = S_sh[6 * l + 0] + S_sh[6 * l + 1] + S_sh[6 * l + 2];
    const float h1 = S_sh[6 * l + 3] + S_sh[6 * l + 4] + S_sh[6 * l + 5];
    const float* fr = feat + (long)n * DF;
    const float o0 = fr[2 * l + 0] + h0 * (1.0f / 96.0f);
    const float o1 = fr[2 * l + 1] + h1 * (1.0f / 96.0f);
    *(float2*)&out[(long)n * DF + 2 * l] = make_float2(o0, o1);
}

extern "C" void kernel_launch(void* const* d_in, const int* in_sizes, int n_in,
                              void* d_out, int out_size, void* d_ws, size_t ws_size,
                              hipStream_t stream) {
    const float* feat = (const float*)d_in[0];
    const int* sim    = (const int*)d_in[1];
    const int* cor    = (const int*)d_in[2];
    float* out        = (float*)d_out;
    const int nnodes  = in_sizes[0] / DF;   // 20000
    const size_t nfeat = (size_t)nnodes * DF;
    const size_t need  = nfeat * 2 + nfeat;   // bf16 copy + fp8 copy

    if (ws_size >= need) {
        unsigned short* featbf = (unsigned short*)d_ws;
        unsigned char*  feat8  = (unsigned char*)d_ws + nfeat * 2;
        const int n8 = (int)(nfeat / 8);
        hipLaunchKernelGGL(cvt_kernel, dim3((n8 + 255) / 256), dim3(256), 0, stream,
                           feat, featbf, feat8, n8);
        const int blocks = (nnodes + WPB - 1) / WPB;   // 5000
        hipLaunchKernelGGL(coattn_kernel, dim3(blocks), dim3(WPB * 64), 0, stream,
                           feat, (const unsigned char*)featbf, feat8, sim, cor, out, nnodes);
    } else {
        hipLaunchKernelGGL(coattn_v4, dim3(nnodes), dim3(64), 0, stream,
                           feat, sim, cor, out, nnodes);
    }
}

// Round 18
// 59.563 us; speedup vs baseline: 1.0055x; 1.0055x over previous
//
#include <hip/hip_runtime.h>

#define KN 32
#define DF 128
#define WPB 2    // waves per block (independent waves, no cross-wave sync)

typedef float  f32x16 __attribute__((ext_vector_type(16)));
typedef float  f32x2  __attribute__((ext_vector_type(2)));
typedef short  s16x8  __attribute__((ext_vector_type(8)));

union ldsu { int4 i; s16x8 v; };

__device__ __forceinline__ unsigned int pk_bf16(float lo, float hi) {
    unsigned int r;
    asm("v_cvt_pk_bf16_f32 %0, %1, %2" : "=v"(r) : "v"(lo), "v"(hi));
    return r;
}
// exp2 — featbf is pre-scaled by sqrt(log2 e), so exp(L-m) == exp2(L'-m').
__device__ __forceinline__ float ex2(float x) {
    float r; asm("v_exp_f32 %0, %1" : "=v"(r) : "v"(x)); return r;
}
__device__ __forceinline__ float bflo(unsigned int u) { return __uint_as_float(u << 16); }
__device__ __forceinline__ float bfhi(unsigned int u) { return __uint_as_float(u & 0xffff0000u); }

// global -> LDS direct copy, 16B per lane; LDS dest = base + lane*16 (HW rule).
__device__ __forceinline__ void gll16(const void* g, void* l) {
    __builtin_amdgcn_global_load_lds(
        (const __attribute__((address_space(1))) unsigned int*)g,
        (__attribute__((address_space(3))) unsigned int*)l,
        16, 0, 0);
}

// ---- Prepass: feat fp32 -> bf16 copy scaled by sqrt(log2 e) (MFMA operands;
// scale cancels in softmax via exp2) + fp8 copy UNSCALED (phase E values).
__global__ __launch_bounds__(256)
void cvt_kernel(const float* __restrict__ f, unsigned short* __restrict__ bf,
                unsigned char* __restrict__ f8, int n8) {
    const int i = blockIdx.x * blockDim.x + threadIdx.x;   // 8 floats per thread
    if (i >= n8) return;
    const float s = 1.20112240872f;   // sqrt(log2(e)); L' = log2e * L exactly
    float4 x0 = ((const float4*)f)[2 * i];
    float4 x1 = ((const float4*)f)[2 * i + 1];
    int4 b;
    b.x = (int)pk_bf16(s * x0.x, s * x0.y); b.y = (int)pk_bf16(s * x0.z, s * x0.w);
    b.z = (int)pk_bf16(s * x1.x, s * x1.y); b.w = (int)pk_bf16(s * x1.z, s * x1.w);
    ((int4*)bf)[i] = b;
    int p0 = __builtin_amdgcn_cvt_pk_fp8_f32(x0.x, x0.y, 0, false);
    p0     = __builtin_amdgcn_cvt_pk_fp8_f32(x0.z, x0.w, p0, true);
    int p1 = __builtin_amdgcn_cvt_pk_fp8_f32(x1.x, x1.y, 0, false);
    p1     = __builtin_amdgcn_cvt_pk_fp8_f32(x1.z, x1.w, p1, true);
    ((int2*)f8)[i] = make_int2(p0, p1);
}

// ---- Main: round-16 (best: 46.9us main) + zero-LDS-cost latency reorder:
// (1) H1's D-stage issued BEFORE H0's MFMAs (buffer free after fQ0 retires),
// (2) phase-E fp8 loads pinned via asm right after H1's Q-stage; counted
// vmcnt(32) for fQ1 (Q1 glls are the oldest 4 in the VMEM FIFO), vmcnt(0)
// before phase-E compute. Numerics identical to R16 (absmax 0.03125).
__global__ __launch_bounds__(WPB * 64, 2)
void coattn_kernel(const float* __restrict__ feat,
                   const unsigned char* __restrict__ featbf,   // bf16 rows, 256B each (scaled)
                   const unsigned char* __restrict__ feat8,    // fp8 rows, 128B each
                   const int* __restrict__ sim_idx,
                   const int* __restrict__ cor_idx,
                   float* __restrict__ out, int nnodes) {
    // [wave][row 32][chunk 8] x 16B = 4KB per wave (one matrix K-half at a time)
    __shared__ int4 Ls[WPB][KN][8];
    const int wv = threadIdx.x >> 6;
    const int l  = threadIdx.x & 63;
    const int c  = l & 31;   // neighbor row owned by this lane (MFMA row/col)
    const int h  = l >> 5;   // wave half
    const int g  = l >> 3;   // cooperative row group 0..7
    const int m  = l & 7;    // 16B chunk within half-row
    const int n  = blockIdx.x * WPB + wv;
    if (n >= nnodes) return;

    const int si = sim_idx[n * KN + c];
    const int ci = cor_idx[n * KN + c];
    const unsigned pidx = ((unsigned)ci << 16) | (unsigned)si;   // both < 2^16
    // Pre-swizzled source chunk (involution m^g): reader XORs with c&7.
    const unsigned swz = (unsigned)(((m ^ g) & 7) * 16);

    f32x16 acc  = {0,0,0,0,0,0,0,0,0,0,0,0,0,0,0,0};
    f32x16 accT = {0,0,0,0,0,0,0,0,0,0,0,0,0,0,0,0};
    unsigned spk[4];
    #pragma unroll
    for (int t = 0; t < 4; ++t) spk[t] = (unsigned)__shfl((int)pidx, 8 * t + g, 64);

    // ---- H0: D stage -> read fD0; Q stage -> read fQ0.
    #pragma unroll
    for (int t = 0; t < 4; ++t)
        gll16(featbf + (spk[t] & 0xffffu) * 256u + swz, (void*)&Ls[wv][8 * t][0]);
    asm volatile("s_waitcnt vmcnt(0)" ::: "memory");
    __builtin_amdgcn_sched_barrier(0);
    s16x8 fD[4], fQ[4];
    #pragma unroll
    for (int sp = 0; sp < 4; ++sp) {
        union ldsu u; u.i = Ls[wv][c][(sp * 2 + h) ^ (c & 7)]; fD[sp] = u.v;
    }
    asm volatile("s_waitcnt lgkmcnt(0)" ::: "memory");   // WAR: D0 reads retired
    __builtin_amdgcn_sched_barrier(0);
    #pragma unroll
    for (int t = 0; t < 4; ++t)
        gll16(featbf + (spk[t] >> 16) * 256u + swz, (void*)&Ls[wv][8 * t][0]);
    asm volatile("s_waitcnt vmcnt(0)" ::: "memory");
    __builtin_amdgcn_sched_barrier(0);
    #pragma unroll
    for (int sp = 0; sp < 4; ++sp) {
        union ldsu u; u.i = Ls[wv][c][(sp * 2 + h) ^ (c & 7)]; fQ[sp] = u.v;
    }
    asm volatile("s_waitcnt lgkmcnt(0)" ::: "memory");   // WAR: Q0 reads retired
    __builtin_amdgcn_sched_barrier(0);

    // ---- H1 D-stage PREFETCH (buffer free), then H0 MFMAs hide its latency.
    #pragma unroll
    for (int t = 0; t < 4; ++t)
        gll16(featbf + (spk[t] & 0xffffu) * 256u + 128u + swz, (void*)&Ls[wv][8 * t][0]);
    #pragma unroll
    for (int sp = 0; sp < 4; ++sp) {
        acc  = __builtin_amdgcn_mfma_f32_32x32x16_bf16(fD[sp], fQ[sp], acc,  0, 0, 0);
        accT = __builtin_amdgcn_mfma_f32_32x32x16_bf16(fQ[sp], fD[sp], accT, 0, 0, 0);
    }
    asm volatile("s_waitcnt vmcnt(0)" ::: "memory");     // D1 landed
    __builtin_amdgcn_sched_barrier(0);
    #pragma unroll
    for (int sp = 0; sp < 4; ++sp) {
        union ldsu u; u.i = Ls[wv][c][(sp * 2 + h) ^ (c & 7)]; fD[sp] = u.v;
    }
    asm volatile("s_waitcnt lgkmcnt(0)" ::: "memory");   // WAR: D1 reads retired
    __builtin_amdgcn_sched_barrier(0);
    // ---- H1 Q-stage, then the 32 pinned phase-E fp8 loads (asm: cannot sink).
    #pragma unroll
    for (int t = 0; t < 4; ++t)
        gll16(featbf + (spk[t] >> 16) * 256u + 128u + swz, (void*)&Ls[wv][8 * t][0]);
    unsigned da[16], dq[16];
    #pragma unroll
    for (int t = 0; t < 16; ++t) {
        const unsigned pi = (unsigned)__shfl((int)pidx, h * 16 + t, 64);
        const unsigned char* pD = feat8 + ((pi & 0xffffu) << 7) + 4u * c;
        const unsigned char* pQ = feat8 + ((pi >> 16) << 7) + 4u * c;
        asm volatile("global_load_dword %0, %1, off" : "=v"(da[t]) : "v"(pD) : "memory");
        asm volatile("global_load_dword %0, %1, off" : "=v"(dq[t]) : "v"(pQ) : "memory");
    }
    // Q1's 4 glls are the oldest outstanding VMEM ops -> vmcnt(32) = Q1 landed.
    asm volatile("s_waitcnt vmcnt(32)" ::: "memory");
    __builtin_amdgcn_sched_barrier(0);
    #pragma unroll
    for (int sp = 0; sp < 4; ++sp) {
        union ldsu u; u.i = Ls[wv][c][(sp * 2 + h) ^ (c & 7)]; fQ[sp] = u.v;
    }
    #pragma unroll
    for (int sp = 0; sp < 4; ++sp) {
        acc  = __builtin_amdgcn_mfma_f32_32x32x16_bf16(fD[sp], fQ[sp], acc,  0, 0, 0);
        accT = __builtin_amdgcn_mfma_f32_32x32x16_bf16(fQ[sp], fD[sp], accT, 0, 0, 0);
    }
    // C layout: elem p at M[row=(p&3)+8*(p>>2)+4*h][col=c]
    // acc[p] = L'[kp][c], accT[p] = L'[c][jp]  (L' = log2e * L)

    // ---- Phase D (exp2 domain, numerically safe; hides phase-E load latency).
    float mx = acc[0];
    #pragma unroll
    for (int p = 1; p < 16; ++p) mx = fmaxf(mx, acc[p]);
    mx = fmaxf(mx, __shfl_xor(mx, 32, 64));
    const float mxf = bfhi(pk_bf16(0.f, mx));          // bf16-rounded max (RNE)
    float z = 0.f;
    #pragma unroll
    for (int p = 0; p < 16; ++p) z += ex2(acc[p] - mxf);
    z += __shfl_xor(z, 32, 64);
    const unsigned pcol = pk_bf16(1.0f / z, mxf);      // lo=bf16(invZ), hi=bf16(mx)

    float rm = accT[0];
    #pragma unroll
    for (int p = 1; p < 16; ++p) rm = fmaxf(rm, accT[p]);
    rm = fmaxf(rm, __shfl_xor(rm, 32, 64));
    const float rmf = bfhi(pk_bf16(0.f, rm));
    float rs = 0.f;
    #pragma unroll
    for (int p = 0; p < 16; ++p) rs += ex2(accT[p] - rmf);
    rs += __shfl_xor(rs, 32, 64);

    // w[b=c] = sum_a exp2(L'[b][a]-mx_a) * invZ_a   (one packed shuffle per p)
    float w = 0.f;
    #pragma unroll
    for (int p = 0; p < 16; ++p) {
        const int jp = (p & 3) + 8 * (p >> 2) + 4 * h;
        const unsigned pc = (unsigned)__shfl((int)pcol, jp, 64);
        w += ex2(accT[p] - bfhi(pc)) * bflo(pc);
    }
    w += __shfl_xor(w, 32, 64);

    // v[j=c] = sum_b u_b * exp2(L'[b][j]-rm_b),  u = w/rs  (packed shuffle)
    const unsigned prow = pk_bf16(w / rs, rmf);        // lo=bf16(u), hi=bf16(rm)
    float v = 0.f;
    #pragma unroll
    for (int p = 0; p < 16; ++p) {
        const int kp = (p & 3) + 8 * (p >> 2) + 4 * h;
        const unsigned pr = (unsigned)__shfl((int)prow, kp, 64);
        v += ex2(acc[p] - bfhi(pr)) * bflo(pr);
    }
    v += __shfl_xor(v, 32, 64);

    // ---- Phase E: weighted row-sums from the preloaded fp8 dwords.
    // Packed (v,w) shuffle; f32x2 accumulation (v_pk_fma_f32). Dims 4c..4c+3.
    const unsigned pwv = pk_bf16(v, w);                // lo=bf16(v), hi=bf16(w)
    asm volatile("s_waitcnt vmcnt(0)" ::: "memory");   // da/dq valid
    __builtin_amdgcn_sched_barrier(0);
    f32x2 sQ2[2] = {{0.f,0.f},{0.f,0.f}};
    f32x2 sD2[2] = {{0.f,0.f},{0.f,0.f}};
    f32x2 sC2[2] = {{0.f,0.f},{0.f,0.f}};
    #pragma unroll
    for (int t = 0; t < 16; ++t) {
        const int b = h * 16 + t;
        const unsigned pv = (unsigned)__shfl((int)pwv, b, 64);
        const float wb = bfhi(pv);
        const float vb = bflo(pv);
        f32x2 a01 = __builtin_amdgcn_cvt_pk_f32_fp8((int)da[t], false);
        f32x2 a23 = __builtin_amdgcn_cvt_pk_f32_fp8((int)da[t], true);
        f32x2 q01 = __builtin_amdgcn_cvt_pk_f32_fp8((int)dq[t], false);
        f32x2 q23 = __builtin_amdgcn_cvt_pk_f32_fp8((int)dq[t], true);
        const f32x2 wb2 = {wb, wb};
        const f32x2 vb2 = {vb, vb};
        sQ2[0] += q01;                sQ2[1] += q23;
        sD2[0] = wb2 * a01 + sD2[0];  sD2[1] = wb2 * a23 + sD2[1];
        sC2[0] = vb2 * q01 + sC2[0];  sC2[1] = vb2 * q23 + sC2[1];
    }
    #pragma unroll
    for (int i = 0; i < 2; ++i) {
        sQ2[i][0] += __shfl_xor(sQ2[i][0], 32, 64); sQ2[i][1] += __shfl_xor(sQ2[i][1], 32, 64);
        sD2[i][0] += __shfl_xor(sD2[i][0], 32, 64); sD2[i][1] += __shfl_xor(sD2[i][1], 32, 64);
        sC2[i][0] += __shfl_xor(sC2[i][0], 32, 64); sC2[i][1] += __shfl_xor(sC2[i][1], 32, 64);
    }

    // ---- Phase F: pooling via S_sh overlaid on this wave's (retired) staging
    // buffer; intra-wave lgkm fence, no barrier.
    float* const S_sh = (float*)Ls[wv];
    if (h == 0) {
        *(float4*)&S_sh[0 * DF + 4 * c] = make_float4(sQ2[0][0], sQ2[0][1], sQ2[1][0], sQ2[1][1]);
        *(float4*)&S_sh[1 * DF + 4 * c] = make_float4(sD2[0][0], sD2[0][1], sD2[1][0], sD2[1][1]);
        *(float4*)&S_sh[2 * DF + 4 * c] = make_float4(sC2[0][0], sC2[0][1], sC2[1][0], sC2[1][1]);
    }
    asm volatile("s_waitcnt lgkmcnt(0)" ::: "memory");
    const float h0 = S_sh[6 * l + 0] + S_sh[6 * l + 1] + S_sh[6 * l + 2];
    const float h1 = S_sh[6 * l + 3] + S_sh[6 * l + 4] + S_sh[6 * l + 5];
    const float* fr = feat + (long)n * DF;
    const float o0 = fr[2 * l + 0] + h0 * (1.0f / 96.0f);
    const float o1 = fr[2 * l + 1] + h1 * (1.0f / 96.0f);
    *(float2*)&out[(long)n * DF + 2 * l] = make_float2(o0, o1);
}

// ---- Fallback (round-4 kernel, fp32-direct): used only if ws_size is too small.
#define RP 136
__global__ __launch_bounds__(64, 2)
void coattn_v4(const float* __restrict__ feat,
               const int* __restrict__ sim_idx,
               const int* __restrict__ cor_idx,
               float* __restrict__ out, int nnodes) {
    __shared__ unsigned char lds[2 * KN * RP];
    unsigned char* Ab8 = lds;
    unsigned char* Bb8 = lds + KN * RP;
    float* S_sh = (float*)lds;
    const int n = blockIdx.x;
    const int l = threadIdx.x;
    const int c = l & 31;
    const int h = l >> 5;
    const int si = sim_idx[n * KN + c];
    const int ci = cor_idx[n * KN + c];
    const float* Dr = feat + (long)si * DF;
    const float* Qr = feat + (long)ci * DF;
    f32x16 acc  = {0,0,0,0,0,0,0,0,0,0,0,0,0,0,0,0};
    f32x16 accT = {0,0,0,0,0,0,0,0,0,0,0,0,0,0,0,0};
    #pragma unroll
    for (int s = 0; s < 8; ++s) {
        const int d0 = s * 16 + h * 8;
        float4 a0 = *(const float4*)(Dr + d0);
        float4 a1 = *(const float4*)(Dr + d0 + 4);
        float4 b0 = *(const float4*)(Qr + d0);
        float4 b1 = *(const float4*)(Qr + d0 + 4);
        union { s16x8 v8; unsigned int u[4]; } ua, ub;
        ua.u[0] = pk_bf16(a0.x, a0.y); ua.u[1] = pk_bf16(a0.z, a0.w);
        ua.u[2] = pk_bf16(a1.x, a1.y); ua.u[3] = pk_bf16(a1.z, a1.w);
        ub.u[0] = pk_bf16(b0.x, b0.y); ub.u[1] = pk_bf16(b0.z, b0.w);
        ub.u[2] = pk_bf16(b1.x, b1.y); ub.u[3] = pk_bf16(b1.z, b1.w);
        acc  = __builtin_amdgcn_mfma_f32_32x32x16_bf16(ua.v8, ub.v8, acc,  0, 0, 0);
        accT = __builtin_amdgcn_mfma_f32_32x32x16_bf16(ub.v8, ua.v8, accT, 0, 0, 0);
        int pa0 = __builtin_amdgcn_cvt_pk_fp8_f32(a0.x, a0.y, 0, false);
        pa0     = __builtin_amdgcn_cvt_pk_fp8_f32(a0.z, a0.w, pa0, true);
        int pa1 = __builtin_amdgcn_cvt_pk_fp8_f32(a1.x, a1.y, 0, false);
        pa1     = __builtin_amdgcn_cvt_pk_fp8_f32(a1.z, a1.w, pa1, true);
        int pb0 = __builtin_amdgcn_cvt_pk_fp8_f32(b0.x, b0.y, 0, false);
        pb0     = __builtin_amdgcn_cvt_pk_fp8_f32(b0.z, b0.w, pb0, true);
        int pb1 = __builtin_amdgcn_cvt_pk_fp8_f32(b1.x, b1.y, 0, false);
        pb1     = __builtin_amdgcn_cvt_pk_fp8_f32(b1.z, b1.w, pb1, true);
        *(int2*)(Ab8 + c * RP + d0) = make_int2(pa0, pa1);
        *(int2*)(Bb8 + c * RP + d0) = make_int2(pb0, pb1);
    }
    float mx = acc[0];
    #pragma unroll
    for (int p = 1; p < 16; ++p) mx = fmaxf(mx, acc[p]);
    mx = fmaxf(mx, __shfl_xor(mx, 32, 64));
    float z = 0.f;
    #pragma unroll
    for (int p = 0; p < 16; ++p) z += __expf(acc[p] - mx);
    z += __shfl_xor(z, 32, 64);
    const float invZ = 1.0f / z;
    float rm = accT[0];
    #pragma unroll
    for (int p = 1; p < 16; ++p) rm = fmaxf(rm, accT[p]);
    rm = fmaxf(rm, __shfl_xor(rm, 32, 64));
    float rs = 0.f;
    #pragma unroll
    for (int p = 0; p < 16; ++p) rs += __expf(accT[p] - rm);
    rs += __shfl_xor(rs, 32, 64);
    const float invR = 1.0f / rs;
    float w = 0.f;
    #pragma unroll
    for (int p = 0; p < 16; ++p) {
        const int jp = (p & 3) + 8 * (p >> 2) + 4 * h;
        w += __expf(accT[p] - __shfl(mx, jp, 64)) * __shfl(invZ, jp, 64);
    }
    w += __shfl_xor(w, 32, 64);
    const float u = w * invR;
    float v = 0.f;
    #pragma unroll
    for (int p = 0; p < 16; ++p) {
        const int kp = (p & 3) + 8 * (p >> 2) + 4 * h;
        v += __expf(acc[p] - __shfl(rm, kp, 64)) * __shfl(u, kp, 64);
    }
    v += __shfl_xor(v, 32, 64);
    __syncthreads();
    float sQ[4] = {0,0,0,0}, sD[4] = {0,0,0,0}, sC[4] = {0,0,0,0};
    const unsigned char* Abase = Ab8 + h * 16 * RP + 4 * c;
    const unsigned char* Bbase = Bb8 + h * 16 * RP + 4 * c;
    #pragma unroll
    for (int t = 0; t < 16; ++t) {
        const int b = h * 16 + t;
        const float wb = __shfl(w, b, 64);
        const float vb = __shfl(v, b, 64);
        const unsigned int da = *(const unsigned int*)(Abase + t * RP);
        const unsigned int dq = *(const unsigned int*)(Bbase + t * RP);
        f32x2 a01 = __builtin_amdgcn_cvt_pk_f32_fp8((int)da, false);
        f32x2 a23 = __builtin_amdgcn_cvt_pk_f32_fp8((int)da, true);
        f32x2 q01 = __builtin_amdgcn_cvt_pk_f32_fp8((int)dq, false);
        f32x2 q23 = __builtin_amdgcn_cvt_pk_f32_fp8((int)dq, true);
        sQ[0] += q01[0]; sQ[1] += q01[1]; sQ[2] += q23[0]; sQ[3] += q23[1];
        sD[0] = fmaf(wb, a01[0], sD[0]); sD[1] = fmaf(wb, a01[1], sD[1]);
        sD[2] = fmaf(wb, a23[0], sD[2]); sD[3] = fmaf(wb, a23[1], sD[3]);
        sC[0] = fmaf(vb, q01[0], sC[0]); sC[1] = fmaf(vb, q01[1], sC[1]);
        sC[2] = fmaf(vb, q23[0], sC[2]);
        sC[3] = fmaf(vb, q23[1], sC[3]);
    }
    #pragma unroll
    for (int i = 0; i < 4; ++i) {
        sQ[i] += __shfl_xor(sQ[i], 32, 64);
        sD[i] += __shfl_xor(sD[i], 32, 64);
        sC[i] += __shfl_xor(sC[i], 32, 64);
    }
    __syncthreads();
    if (h == 0) {
        *(float4*)&S_sh[0 * DF + 4 * c] = make_float4(sQ[0], sQ[1], sQ[2], sQ[3]);
        *(float4*)&S_sh[1 * DF + 4 * c] = make_float4(sD[0], sD[1], sD[2], sD[3]);
        *(float4*)&S_sh[2 * DF + 4 * c] = make_float4(sC[0], sC[1], sC[2], sC[3]);
    }
    __syncthreads();
    const float h0 = S_sh[6 * l + 0] + S_sh[6 * l + 1] + S_sh[6 * l + 2];
    const float h1 = S_sh[6 * l + 3] + S_sh[6 * l + 4] + S_sh[6 * l + 5];
    const float* fr = feat + (long)n * DF;
    const float o0 = fr[2 * l + 0] + h0 * (1.0f / 96.0f);
    const float o1 = fr[2 * l + 1] + h1 * (1.0f / 96.0f);
    *(float2*)&out[(long)n * DF + 2 * l] = make_float2(o0, o1);
}

extern "C" void kernel_launch(void* const* d_in, const int* in_sizes, int n_in,
                              void* d_out, int out_size, void* d_ws, size_t ws_size,
                              hipStream_t stream) {
    const float* feat = (const float*)d_in[0];
    const int* sim    = (const int*)d_in[1];
    const int* cor    = (const int*)d_in[2];
    float* out        = (float*)d_out;
    const int nnodes  = in_sizes[0] / DF;   // 20000
    const size_t nfeat = (size_t)nnodes * DF;
    const size_t need  = nfeat * 2 + nfeat;   // bf16 copy + fp8 copy

    if (ws_size >= need) {
        unsigned short* featbf = (unsigned short*)d_ws;
        unsigned char*  feat8  = (unsigned char*)d_ws + nfeat * 2;
        const int n8 = (int)(nfeat / 8);
        hipLaunchKernelGGL(cvt_kernel, dim3((n8 + 255) / 256), dim3(256), 0, stream,
                           feat, featbf, feat8, n8);
        const int blocks = (nnodes + WPB - 1) / WPB;   // 10000
        hipLaunchKernelGGL(coattn_kernel, dim3(blocks), dim3(WPB * 64), 0, stream,
                           feat, (const unsigned char*)featbf, feat8, sim, cor, out, nnodes);
    } else {
        hipLaunchKernelGGL(coattn_v4, dim3(nnodes), dim3(64), 0, stream,
                           feat, sim, cor, out, nnodes);
    }
}

// Round 19
// 54.607 us; speedup vs baseline: 1.0967x; 1.0908x over previous
//
#include <hip/hip_runtime.h>

#define KN 32
#define DF 128
#define WPB 2    // waves per block (independent waves, no cross-wave sync)

typedef float  f32x16 __attribute__((ext_vector_type(16)));
typedef float  f32x2  __attribute__((ext_vector_type(2)));
typedef short  s16x8  __attribute__((ext_vector_type(8)));

union ldsu { int4 i; s16x8 v; };

__device__ __forceinline__ unsigned int pk_bf16(float lo, float hi) {
    unsigned int r;
    asm("v_cvt_pk_bf16_f32 %0, %1, %2" : "=v"(r) : "v"(lo), "v"(hi));
    return r;
}
// exp2 — featbf is pre-scaled by sqrt(log2 e), so exp(L-m) == exp2(L'-m').
__device__ __forceinline__ float ex2(float x) {
    float r; asm("v_exp_f32 %0, %1" : "=v"(r) : "v"(x)); return r;
}
__device__ __forceinline__ float bflo(unsigned int u) { return __uint_as_float(u << 16); }
__device__ __forceinline__ float bfhi(unsigned int u) { return __uint_as_float(u & 0xffff0000u); }

// global -> LDS direct copy, 16B per lane; LDS dest = base + lane*16 (HW rule).
__device__ __forceinline__ void gll16(const void* g, void* l) {
    __builtin_amdgcn_global_load_lds(
        (const __attribute__((address_space(1))) unsigned int*)g,
        (__attribute__((address_space(3))) unsigned int*)l,
        16, 0, 0);
}

// ---- Prepass: feat fp32 -> bf16 copy scaled by sqrt(log2 e) (MFMA operands;
// scale cancels in softmax via exp2) + fp8 copy UNSCALED (phase E values).
__global__ __launch_bounds__(256)
void cvt_kernel(const float* __restrict__ f, unsigned short* __restrict__ bf,
                unsigned char* __restrict__ f8, int n8) {
    const int i = blockIdx.x * blockDim.x + threadIdx.x;   // 8 floats per thread
    if (i >= n8) return;
    const float s = 1.20112240872f;   // sqrt(log2(e)); L' = log2e * L exactly
    float4 x0 = ((const float4*)f)[2 * i];
    float4 x1 = ((const float4*)f)[2 * i + 1];
    int4 b;
    b.x = (int)pk_bf16(s * x0.x, s * x0.y); b.y = (int)pk_bf16(s * x0.z, s * x0.w);
    b.z = (int)pk_bf16(s * x1.x, s * x1.y); b.w = (int)pk_bf16(s * x1.z, s * x1.w);
    ((int4*)bf)[i] = b;
    int p0 = __builtin_amdgcn_cvt_pk_fp8_f32(x0.x, x0.y, 0, false);
    p0     = __builtin_amdgcn_cvt_pk_fp8_f32(x0.z, x0.w, p0, true);
    int p1 = __builtin_amdgcn_cvt_pk_fp8_f32(x1.x, x1.y, 0, false);
    p1     = __builtin_amdgcn_cvt_pk_fp8_f32(x1.z, x1.w, p1, true);
    ((int2*)f8)[i] = make_int2(p0, p1);
}

// ---- Main: round-16 exact (best measured: 46.9us main / 54.9us total).
// Structure: 1 wave/node; cooperative gather via global_load_lds into a
// single 4KB/wave buffer (D then Q per K-half); MFMA 32x32x16 computes L and
// L^T; numerically-safe packed-bf16-stat softmax in exp2 domain; fp8-table
// phase E with packed shuffles + v_pk_fma_f32; LDS pooling, no barriers.
__global__ __launch_bounds__(WPB * 64, 2)
void coattn_kernel(const float* __restrict__ feat,
                   const unsigned char* __restrict__ featbf,   // bf16 rows, 256B each (scaled)
                   const unsigned char* __restrict__ feat8,    // fp8 rows, 128B each
                   const int* __restrict__ sim_idx,
                   const int* __restrict__ cor_idx,
                   float* __restrict__ out, int nnodes) {
    // [wave][row 32][chunk 8] x 16B = 4KB per wave (one matrix K-half at a time)
    __shared__ int4 Ls[WPB][KN][8];
    const int wv = threadIdx.x >> 6;
    const int l  = threadIdx.x & 63;
    const int c  = l & 31;   // neighbor row owned by this lane (MFMA row/col)
    const int h  = l >> 5;   // wave half
    const int g  = l >> 3;   // cooperative row group 0..7
    const int m  = l & 7;    // 16B chunk within half-row
    const int n  = blockIdx.x * WPB + wv;
    if (n >= nnodes) return;

    const int si = sim_idx[n * KN + c];
    const int ci = cor_idx[n * KN + c];
    const unsigned pidx = ((unsigned)ci << 16) | (unsigned)si;   // both < 2^16
    // Pre-swizzled source chunk (involution m^g): reader XORs with c&7.
    const unsigned swz = (unsigned)(((m ^ g) & 7) * 16);

    // ---- Phase A+C: per K-half: stage D -> read fD, stage Q -> MFMA.
    // Fragment layout for mfma_f32_32x32x16_bf16: lane (c,h) holds row c,
    // k = h*8+e per K=16 step s -> 16B chunk (sp*2+h) of the half.
    f32x16 acc  = {0,0,0,0,0,0,0,0,0,0,0,0,0,0,0,0};
    f32x16 accT = {0,0,0,0,0,0,0,0,0,0,0,0,0,0,0,0};
    unsigned spk[4];
    #pragma unroll
    for (int t = 0; t < 4; ++t) spk[t] = (unsigned)__shfl((int)pidx, 8 * t + g, 64);
    #pragma unroll
    for (int H = 0; H < 2; ++H) {
        const unsigned hoff = (unsigned)(H * 128) + swz;
        // -- D stage
        #pragma unroll
        for (int t = 0; t < 4; ++t)
            gll16(featbf + (spk[t] & 0xffffu) * 256u + hoff, (void*)&Ls[wv][8 * t][0]);
        asm volatile("s_waitcnt vmcnt(0)" ::: "memory");   // LDS writes landed
        __builtin_amdgcn_sched_barrier(0);
        s16x8 fD[4];
        #pragma unroll
        for (int sp = 0; sp < 4; ++sp) {
            union ldsu u; u.i = Ls[wv][c][(sp * 2 + h) ^ (c & 7)];
            fD[sp] = u.v;
        }
        asm volatile("s_waitcnt lgkmcnt(0)" ::: "memory"); // WAR: D reads done
        __builtin_amdgcn_sched_barrier(0);
        // -- Q stage (overwrites buffer)
        #pragma unroll
        for (int t = 0; t < 4; ++t)
            gll16(featbf + (spk[t] >> 16) * 256u + hoff, (void*)&Ls[wv][8 * t][0]);
        asm volatile("s_waitcnt vmcnt(0)" ::: "memory");
        __builtin_amdgcn_sched_barrier(0);
        #pragma unroll
        for (int sp = 0; sp < 4; ++sp) {
            union ldsu uQ; uQ.i = Ls[wv][c][(sp * 2 + h) ^ (c & 7)];
            acc  = __builtin_amdgcn_mfma_f32_32x32x16_bf16(fD[sp], uQ.v, acc,  0, 0, 0);
            accT = __builtin_amdgcn_mfma_f32_32x32x16_bf16(uQ.v, fD[sp], accT, 0, 0, 0);
        }
        asm volatile("s_waitcnt lgkmcnt(0)" ::: "memory"); // WAR before next stage
        __builtin_amdgcn_sched_barrier(0);
    }
    // C layout: elem p at M[row=(p&3)+8*(p>>2)+4*h][col=c]
    // acc[p] = L'[kp][c], accT[p] = L'[c][jp]  (L' = log2e * L)

    // ---- Phase D (exp2 domain, numerically safe). Column stats for col c:
    // round mx to bf16 FIRST, compute z against the rounded max -> the packed
    // bf16 (invZ,mx) shuffle stays exactly self-consistent. Args <= ~0.5,
    // denominators >= 1: safe even for collision diagonals (L' ~ 185).
    float mx = acc[0];
    #pragma unroll
    for (int p = 1; p < 16; ++p) mx = fmaxf(mx, acc[p]);
    mx = fmaxf(mx, __shfl_xor(mx, 32, 64));
    const float mxf = bfhi(pk_bf16(0.f, mx));          // bf16-rounded max (RNE)
    float z = 0.f;
    #pragma unroll
    for (int p = 0; p < 16; ++p) z += ex2(acc[p] - mxf);
    z += __shfl_xor(z, 32, 64);
    const unsigned pcol = pk_bf16(1.0f / z, mxf);      // lo=bf16(invZ), hi=bf16(mx)

    float rm = accT[0];
    #pragma unroll
    for (int p = 1; p < 16; ++p) rm = fmaxf(rm, accT[p]);
    rm = fmaxf(rm, __shfl_xor(rm, 32, 64));
    const float rmf = bfhi(pk_bf16(0.f, rm));
    float rs = 0.f;
    #pragma unroll
    for (int p = 0; p < 16; ++p) rs += ex2(accT[p] - rmf);
    rs += __shfl_xor(rs, 32, 64);

    // w[b=c] = sum_a exp2(L'[b][a]-mx_a) * invZ_a   (one packed shuffle per p)
    float w = 0.f;
    #pragma unroll
    for (int p = 0; p < 16; ++p) {
        const int jp = (p & 3) + 8 * (p >> 2) + 4 * h;
        const unsigned pc = (unsigned)__shfl((int)pcol, jp, 64);
        w += ex2(accT[p] - bfhi(pc)) * bflo(pc);
    }
    w += __shfl_xor(w, 32, 64);

    // v[j=c] = sum_b u_b * exp2(L'[b][j]-rm_b),  u = w/rs  (packed shuffle)
    const unsigned prow = pk_bf16(w / rs, rmf);        // lo=bf16(u), hi=bf16(rm)
    float v = 0.f;
    #pragma unroll
    for (int p = 0; p < 16; ++p) {
        const int kp = (p & 3) + 8 * (p >> 2) + 4 * h;
        const unsigned pr = (unsigned)__shfl((int)prow, kp, 64);
        v += ex2(acc[p] - bfhi(pr)) * bflo(pr);
    }
    v += __shfl_xor(v, 32, 64);

    // ---- Phase E: weighted row-sums from the fp8 copy (2.56MB, L2-resident;
    // one 128B line per half-wave load). Packed (v,w) + packed index shuffles;
    // f32x2 accumulation (v_pk_fma_f32). Lane covers dims 4c..4c+3.
    const unsigned pwv = pk_bf16(v, w);                // lo=bf16(v), hi=bf16(w)
    f32x2 sQ2[2] = {{0.f,0.f},{0.f,0.f}};
    f32x2 sD2[2] = {{0.f,0.f},{0.f,0.f}};
    f32x2 sC2[2] = {{0.f,0.f},{0.f,0.f}};
    #pragma unroll
    for (int t = 0; t < 16; ++t) {
        const int b = h * 16 + t;
        const unsigned pi = (unsigned)__shfl((int)pidx, b, 64);
        const unsigned pv = (unsigned)__shfl((int)pwv,  b, 64);
        const float wb = bfhi(pv);
        const float vb = bflo(pv);
        const unsigned int da = *(const unsigned int*)(feat8 + ((pi & 0xffffu) << 7) + 4u * c);
        const unsigned int dq = *(const unsigned int*)(feat8 + ((pi >> 16) << 7) + 4u * c);
        f32x2 a01 = __builtin_amdgcn_cvt_pk_f32_fp8((int)da, false);
        f32x2 a23 = __builtin_amdgcn_cvt_pk_f32_fp8((int)da, true);
        f32x2 q01 = __builtin_amdgcn_cvt_pk_f32_fp8((int)dq, false);
        f32x2 q23 = __builtin_amdgcn_cvt_pk_f32_fp8((int)dq, true);
        const f32x2 wb2 = {wb, wb};
        const f32x2 vb2 = {vb, vb};
        sQ2[0] += q01;                sQ2[1] += q23;
        sD2[0] = wb2 * a01 + sD2[0];  sD2[1] = wb2 * a23 + sD2[1];
        sC2[0] = vb2 * q01 + sC2[0];  sC2[1] = vb2 * q23 + sC2[1];
    }
    #pragma unroll
    for (int i = 0; i < 2; ++i) {
        sQ2[i][0] += __shfl_xor(sQ2[i][0], 32, 64); sQ2[i][1] += __shfl_xor(sQ2[i][1], 32, 64);
        sD2[i][0] += __shfl_xor(sD2[i][0], 32, 64); sD2[i][1] += __shfl_xor(sD2[i][1], 32, 64);
        sC2[i][0] += __shfl_xor(sC2[i][0], 32, 64); sC2[i][1] += __shfl_xor(sC2[i][1], 32, 64);
    }

    // ---- Phase F: pooling via S_sh overlaid on this wave's (retired) staging
    // buffer; intra-wave lgkm fence, no barrier.
    float* const S_sh = (float*)Ls[wv];
    if (h == 0) {
        *(float4*)&S_sh[0 * DF + 4 * c] = make_float4(sQ2[0][0], sQ2[0][1], sQ2[1][0], sQ2[1][1]);
        *(float4*)&S_sh[1 * DF + 4 * c] = make_float4(sD2[0][0], sD2[0][1], sD2[1][0], sD2[1][1]);
        *(float4*)&S_sh[2 * DF + 4 * c] = make_float4(sC2[0][0], sC2[0][1], sC2[1][0], sC2[1][1]);
    }
    asm volatile("s_waitcnt lgkmcnt(0)" ::: "memory");
    const float h0 = S_sh[6 * l + 0] + S_sh[6 * l + 1] + S_sh[6 * l + 2];
    const float h1 = S_sh[6 * l + 3] + S_sh[6 * l + 4] + S_sh[6 * l + 5];
    const float* fr = feat + (long)n * DF;
    const float o0 = fr[2 * l + 0] + h0 * (1.0f / 96.0f);
    const float o1 = fr[2 * l + 1] + h1 * (1.0f / 96.0f);
    *(float2*)&out[(long)n * DF + 2 * l] = make_float2(o0, o1);
}

// ---- Fallback (round-4 kernel, fp32-direct): used only if ws_size is too small.
#define RP 136
__global__ __launch_bounds__(64, 2)
void coattn_v4(const float* __restrict__ feat,
               const int* __restrict__ sim_idx,
               const int* __restrict__ cor_idx,
               float* __restrict__ out, int nnodes) {
    __shared__ unsigned char lds[2 * KN * RP];
    unsigned char* Ab8 = lds;
    unsigned char* Bb8 = lds + KN * RP;
    float* S_sh = (float*)lds;
    const int n = blockIdx.x;
    const int l = threadIdx.x;
    const int c = l & 31;
    const int h = l >> 5;
    const int si = sim_idx[n * KN + c];
    const int ci = cor_idx[n * KN + c];
    const float* Dr = feat + (long)si * DF;
    const float* Qr = feat + (long)ci * DF;
    f32x16 acc  = {0,0,0,0,0,0,0,0,0,0,0,0,0,0,0,0};
    f32x16 accT = {0,0,0,0,0,0,0,0,0,0,0,0,0,0,0,0};
    #pragma unroll
    for (int s = 0; s < 8; ++s) {
        const int d0 = s * 16 + h * 8;
        float4 a0 = *(const float4*)(Dr + d0);
        float4 a1 = *(const float4*)(Dr + d0 + 4);
        float4 b0 = *(const float4*)(Qr + d0);
        float4 b1 = *(const float4*)(Qr + d0 + 4);
        union { s16x8 v8; unsigned int u[4]; } ua, ub;
        ua.u[0] = pk_bf16(a0.x, a0.y); ua.u[1] = pk_bf16(a0.z, a0.w);
        ua.u[2] = pk_bf16(a1.x, a1.y); ua.u[3] = pk_bf16(a1.z, a1.w);
        ub.u[0] = pk_bf16(b0.x, b0.y); ub.u[1] = pk_bf16(b0.z, b0.w);
        ub.u[2] = pk_bf16(b1.x, b1.y); ub.u[3] = pk_bf16(b1.z, b1.w);
        acc  = __builtin_amdgcn_mfma_f32_32x32x16_bf16(ua.v8, ub.v8, acc,  0, 0, 0);
        accT = __builtin_amdgcn_mfma_f32_32x32x16_bf16(ub.v8, ua.v8, accT, 0, 0, 0);
        int pa0 = __builtin_amdgcn_cvt_pk_fp8_f32(a0.x, a0.y, 0, false);
        pa0     = __builtin_amdgcn_cvt_pk_fp8_f32(a0.z, a0.w, pa0, true);
        int pa1 = __builtin_amdgcn_cvt_pk_fp8_f32(a1.x, a1.y, 0, false);
        pa1     = __builtin_amdgcn_cvt_pk_fp8_f32(a1.z, a1.w, pa1, true);
        int pb0 = __builtin_amdgcn_cvt_pk_fp8_f32(b0.x, b0.y, 0, false);
        pb0     = __builtin_amdgcn_cvt_pk_fp8_f32(b0.z, b0.w, pb0, true);
        int pb1 = __builtin_amdgcn_cvt_pk_fp8_f32(b1.x, b1.y, 0, false);
        pb1     = __builtin_amdgcn_cvt_pk_fp8_f32(b1.z, b1.w, pb1, true);
        *(int2*)(Ab8 + c * RP + d0) = make_int2(pa0, pa1);
        *(int2*)(Bb8 + c * RP + d0) = make_int2(pb0, pb1);
    }
    float mx = acc[0];
    #pragma unroll
    for (int p = 1; p < 16; ++p) mx = fmaxf(mx, acc[p]);
    mx = fmaxf(mx, __shfl_xor(mx, 32, 64));
    float z = 0.f;
    #pragma unroll
    for (int p = 0; p < 16; ++p) z += __expf(acc[p] - mx);
    z += __shfl_xor(z, 32, 64);
    const float invZ = 1.0f / z;
    float rm = accT[0];
    #pragma unroll
    for (int p = 1; p < 16; ++p) rm = fmaxf(rm, accT[p]);
    rm = fmaxf(rm, __shfl_xor(rm, 32, 64));
    float rs = 0.f;
    #pragma unroll
    for (int p = 0; p < 16; ++p) rs += __expf(accT[p] - rm);
    rs += __shfl_xor(rs, 32, 64);
    const float invR = 1.0f / rs;
    float w = 0.f;
    #pragma unroll
    for (int p = 0; p < 16; ++p) {
        const int jp = (p & 3) + 8 * (p >> 2) + 4 * h;
        w += __expf(accT[p] - __shfl(mx, jp, 64)) * __shfl(invZ, jp, 64);
    }
    w += __shfl_xor(w, 32, 64);
    const float u = w * invR;
    float v = 0.f;
    #pragma unroll
    for (int p = 0; p < 16; ++p) {
        const int kp = (p & 3) + 8 * (p >> 2) + 4 * h;
        v += __expf(acc[p] - __shfl(rm, kp, 64)) * __shfl(u, kp, 64);
    }
    v += __shfl_xor(v, 32, 64);
    __syncthreads();
    float sQ[4] = {0,0,0,0}, sD[4] = {0,0,0,0}, sC[4] = {0,0,0,0};
    const unsigned char* Abase = Ab8 + h * 16 * RP + 4 * c;
    const unsigned char* Bbase = Bb8 + h * 16 * RP + 4 * c;
    #pragma unroll
    for (int t = 0; t < 16; ++t) {
        const int b = h * 16 + t;
        const float wb = __shfl(w, b, 64);
        const float vb = __shfl(v, b, 64);
        const unsigned int da = *(const unsigned int*)(Abase + t * RP);
        const unsigned int dq = *(const unsigned int*)(Bbase + t * RP);
        f32x2 a01 = __builtin_amdgcn_cvt_pk_f32_fp8((int)da, false);
        f32x2 a23 = __builtin_amdgcn_cvt_pk_f32_fp8((int)da, true);
        f32x2 q01 = __builtin_amdgcn_cvt_pk_f32_fp8((int)dq, false);
        f32x2 q23 = __builtin_amdgcn_cvt_pk_f32_fp8((int)dq, true);
        sQ[0] += q01[0]; sQ[1] += q01[1]; sQ[2] += q23[0]; sQ[3] += q23[1];
        sD[0] = fmaf(wb, a01[0], sD[0]); sD[1] = fmaf(wb, a01[1], sD[1]);
        sD[2] = fmaf(wb, a23[0], sD[2]); sD[3] = fmaf(wb, a23[1], sD[3]);
        sC[0] = fmaf(vb, q01[0], sC[0]); sC[1] = fmaf(vb, q01[1], sC[1]);
        sC[2] = fmaf(vb, q23[0], sC[2]);
        sC[3] = fmaf(vb, q23[1], sC[3]);
    }
    #pragma unroll
    for (int i = 0; i < 4; ++i) {
        sQ[i] += __shfl_xor(sQ[i], 32, 64);
        sD[i] += __shfl_xor(sD[i], 32, 64);
        sC[i] += __shfl_xor(sC[i], 32, 64);
    }
    __syncthreads();
    if (h == 0) {
        *(float4*)&S_sh[0 * DF + 4 * c] = make_float4(sQ[0], sQ[1], sQ[2], sQ[3]);
        *(float4*)&S_sh[1 * DF + 4 * c] = make_float4(sD[0], sD[1], sD[2], sD[3]);
        *(float4*)&S_sh[2 * DF + 4 * c] = make_float4(sC[0], sC[1], sC[2], sC[3]);
    }
    __syncthreads();
    const float h0 = S_sh[6 * l + 0] + S_sh[6 * l + 1] + S_sh[6 * l + 2];
    const float h1 = S_sh[6 * l + 3] + S_sh[6 * l + 4] + S_sh[6 * l + 5];
    const float* fr = feat + (long)n * DF;
    const float o0 = fr[2 * l + 0] + h0 * (1.0f / 96.0f);
    const float o1 = fr[2 * l + 1] + h1 * (1.0f / 96.0f);
    *(float2*)&out[(long)n * DF + 2 * l] = make_float2(o0, o1);
}

extern "C" void kernel_launch(void* const* d_in, const int* in_sizes, int n_in,
                              void* d_out, int out_size, void* d_ws, size_t ws_size,
                              hipStream_t stream) {
    const float* feat = (const float*)d_in[0];
    const int* sim    = (const int*)d_in[1];
    const int* cor    = (const int*)d_in[2];
    float* out        = (float*)d_out;
    const int nnodes  = in_sizes[0] / DF;   // 20000
    const size_t nfeat = (size_t)nnodes * DF;
    const size_t need  = nfeat * 2 + nfeat;   // bf16 copy + fp8 copy

    if (ws_size >= need) {
        unsigned short* featbf = (unsigned short*)d_ws;
        unsigned char*  feat8  = (unsigned char*)d_ws + nfeat * 2;
        const int n8 = (int)(nfeat / 8);
        hipLaunchKernelGGL(cvt_kernel, dim3((n8 + 255) / 256), dim3(256), 0, stream,
                           feat, featbf, feat8, n8);
        const int blocks = (nnodes + WPB - 1) / WPB;   // 10000
        hipLaunchKernelGGL(coattn_kernel, dim3(blocks), dim3(WPB * 64), 0, stream,
                           feat, (const unsigned char*)featbf, feat8, sim, cor, out, nnodes);
    } else {
        hipLaunchKernelGGL(coattn_v4, dim3(nnodes), dim3(64), 0, stream,
                           feat, sim, cor, out, nnodes);
    }
}